// Round 17
// baseline (298.696 us; speedup 1.0000x reference)
//
#include <hip/hip_runtime.h>
#include <hip/hip_bf16.h>

#define B_    32
#define CIN   128
#define COUT  128
#define NN    128
#define PPAD  130                   // padded p dimension (1 zero col each side)
#define ROWE  (PPAD * CIN)          // 16640 ushorts per padded xT row

// LDS x-tile: 4 rows x 66 cols x 128 ch, chunked as [r][j][slot16][8ch]
#define JCOLS 66
#define CHROW (JCOLS * 16)          // 1056 chunks per row
#define CHT   (4 * CHROW)           // 4224 chunks per block tile

typedef __attribute__((ext_vector_type(8))) short short8;
typedef __attribute__((ext_vector_type(4))) float float4v;

static __device__ inline unsigned short f2bf(float f) {
    union { float f; unsigned u; } v; v.f = f;
    unsigned u = v.u;
    unsigned r = u + 0x7FFFu + ((u >> 16) & 1u);   // RNE
    return (unsigned short)(r >> 16);
}

// async 16B global->LDS copy (dest = firstlane base + lane*16; keep issue
// wave-uniform; global src may be per-lane)
static __device__ inline void gll16(const unsigned short* g, unsigned short* l) {
    __builtin_amdgcn_global_load_lds((const __attribute__((address_space(1))) unsigned int*)g,
                                     (__attribute__((address_space(3))) unsigned int*)l,
                                     16, 0, 0);
}

// ---------------------------------------------------------------------------
// x [B][C][N][N] f32 -> xT [B][row][PPAD][128c] bf16, PRE-SWIZZLED:
// 16B chunk at (pp, slot j) holds channels (j ^ (pp&15))*8 .. +7.
// zero cols pp=0,129. One block per (b,row).
// ---------------------------------------------------------------------------
__global__ __launch_bounds__(256) void xpose_kernel(const float* __restrict__ x,
                                                    unsigned short* __restrict__ xT) {
    int b = blockIdx.x >> 7;
    int i = blockIdx.x & 127;
    __shared__ unsigned short tile[CIN * PPAD];   // [c][p], row stride 130
    int tid = threadIdx.x;
    const float* src = x + ((size_t)(b * CIN) * NN + i) * NN;  // x[b][0][i][0]
    #pragma unroll
    for (int e = 0; e < 64; ++e) {
        int idx = e * 256 + tid;
        int c = idx >> 7;
        int p = idx & 127;
        tile[c * PPAD + p] = f2bf(src[(size_t)c * (NN * NN) + p]);
    }
    __syncthreads();
    unsigned short* dst = xT + (size_t)(b * NN + i) * ROWE;
    #pragma unroll
    for (int e = 0; e < 32; ++e) {
        int pi = e * 256 + tid;          // 0..8191
        int c2 = (pi & 63) * 2;
        int p  = pi >> 6;
        ushort2 v;
        v.x = tile[c2 * PPAD + p];
        v.y = tile[(c2 + 1) * PPAD + p];
        int pp = p + 1;
        int sl = (c2 >> 3) ^ (pp & 15);              // baked XOR swizzle
        *(ushort2*)(dst + (size_t)pp * CIN + sl * 8 + (c2 & 7)) = v;
    }
    if (tid < 128) {                                  // zero pad cols
        dst[tid] = 0;
        dst[(size_t)129 * CIN + tid] = 0;
    }
}

// ---------------------------------------------------------------------------
// kernel [O][C][3][3] f32 -> kT2 [kd][cslot16][o][8c] bf16  (kd = k*3+d)
// (v6 layout: wave A-read = 4 x 256B-contiguous windows)
// ---------------------------------------------------------------------------
__global__ __launch_bounds__(256) void ktrans_kernel(const float* __restrict__ kern,
                                                     unsigned short* __restrict__ kT2) {
    int idx = blockIdx.x * 256 + threadIdx.x;     // 0..147455
    if (idx >= COUT * CIN * 9) return;
    int c  = idx & 127;
    int o  = (idx >> 7) & 127;
    int kd = idx >> 14;                           // 0..8
    int k = kd / 3, d = kd % 3;
    float v = kern[(((size_t)o * CIN + c) * 3 + k) * 3 + d];
    kT2[((size_t)(kd * 16 + (c >> 3)) * 128 + o) * 8 + (c & 7)] = f2bf(v);
}

// ---------------------------------------------------------------------------
// main v17 = v12 + sched_barrier(0) pinning. Barrier-free main loop, block =
// 2 rows x 64 px x 128 o (8 waves), 67.6 KB LDS -> 2 blocks/CU (4 waves/SIMD).
// A global->VGPR, B swizzled LDS. Explicit ring-2 fragment buffers; a
// __builtin_amdgcn_sched_barrier(0) between the prefetch-issue block and the
// MFMA cluster forbids the compiler from sinking/serializing the prefetch
// (v12's failure: VGPR=64 showed the double-buffer was demoted). Compiler
// still inserts its own counted waits before consuming MFMAs -> correct.
// ---------------------------------------------------------------------------
__global__ __launch_bounds__(512, 4) void conv_mfma17_kernel(
        const unsigned short* __restrict__ xT,
        const unsigned short* __restrict__ kT2,
        float* __restrict__ out) {
    __shared__ unsigned short xs[CHT * 8];   // 67,584 B

    // bijective XCD swizzle: 4096 blocks, 8 XCDs, 512-block contiguous slabs
    int wg = blockIdx.x;
    int lb = (wg & 7) * 512 + (wg >> 3);
    int b  = lb >> 7;            // image
    int t  = lb & 127;
    int ph_px = t >> 6;          // px half (0/1)
    int rp = t & 63;             // row pair
    const int pb0 = ph_px * 64;

    int tid  = threadIdx.x;
    int lane = tid & 63;
    int wave = tid >> 6;
    int wo = wave >> 2;            // o half (0/1)
    int wr = (wave >> 1) & 1;      // row of pair
    int wp = wave & 1;             // px 32-half
    int ob  = wo * 64;
    int l15 = lane & 15;
    int lg  = lane >> 4;           // 0..3

    // ---- stage 4 x-rows (rp*2-1 .. rp*2+2), cols pb0..pb0+65, clamped ----
    {
        const unsigned short* xrow_base = xT + (size_t)b * NN * ROWE;
        #pragma unroll
        for (int s = 0; s < 9; ++s) {
            int W = s * 512 + tid;
            if (W < CHT) {                       // full waves (4224 = 66*64)
                int r    = W / CHROW;            // 0..3
                int rem  = W - r * CHROW;        // j*16 + slot
                int grow = rp * 2 - 1 + r;       // -1..128
                int growc = grow < 0 ? 0 : (grow > NN - 1 ? NN - 1 : grow);
                gll16(xrow_base + (size_t)growc * ROWE
                          + ((size_t)pb0 + (rem >> 4)) * CIN + (rem & 15) * 8,
                      xs + (size_t)W * 8);
            }
        }
    }
    __syncthreads();   // drains vmcnt -> staged data visible

    // ---- zero halo rows outside the image (block-uniform branches) ----
    if (rp == 0) {
        for (int W = tid; W < CHROW; W += 512)                    // row r=0
            *(short8*)(xs + (size_t)W * 8) = (short8)(0);
    }
    if (rp == 63) {
        for (int W = 3 * CHROW + tid; W < 4 * CHROW; W += 512)    // row r=3
            *(short8*)(xs + (size_t)W * 8) = (short8)(0);
    }
    if (rp == 0 || rp == 63) __syncthreads();

    float4v acc[4][2];
    #pragma unroll
    for (int m = 0; m < 4; ++m) {
        acc[m][0] = (float4v)(0.0f);
        acc[m][1] = (float4v)(0.0f);
    }

    short8 aR[2][4], bR[2][2];

    // ---- preload phase-0 fragments (kd=0 -> k=0,d=0; cc=0) ----
    {
        const unsigned short* krow = kT2;        // kd=0
        #pragma unroll
        for (int m = 0; m < 4; ++m)
            aR[0][m] = *(const short8*)(krow + ((size_t)(lg * 128) + ob + m * 16 + l15) * 8);
        const unsigned short* srow = xs + (size_t)wr * CHROW * 8;
        int j0 = wp * 32 + l15;
        int j1 = j0 + 16;
        bR[0][0] = *(const short8*)(srow + ((size_t)j0 * 16 + (lg ^ (j0 & 15))) * 8);
        bR[0][1] = *(const short8*)(srow + ((size_t)j1 * 16 + (lg ^ (j1 & 15))) * 8);
    }

    // ---- 36 phases, barrier-free; prefetch ph+1 pinned before ph's MFMAs ----
    #pragma unroll
    for (int ph = 0; ph < 36; ++ph) {
        const int q = ph & 1;
        if (ph < 35) {
            const int p1  = ph + 1;
            const int kd1 = p1 >> 2, cc1 = p1 & 3;
            const int k1  = kd1 / 3, d1 = kd1 % 3;
            const int cslot1 = cc1 * 4 + lg;
            const unsigned short* krow = kT2 + (size_t)kd1 * 16 * 128 * 8;
            #pragma unroll
            for (int m = 0; m < 4; ++m)
                aR[q ^ 1][m] = *(const short8*)(krow +
                    ((size_t)(cslot1 * 128) + ob + m * 16 + l15) * 8);
            const unsigned short* srow = xs + (size_t)(wr + k1) * CHROW * 8;
            int j0 = wp * 32 + l15 + d1;         // 0..65 local col
            int j1 = j0 + 16;
            bR[q ^ 1][0] = *(const short8*)(srow + ((size_t)j0 * 16 + (cslot1 ^ (j0 & 15))) * 8);
            bR[q ^ 1][1] = *(const short8*)(srow + ((size_t)j1 * 16 + (cslot1 ^ (j1 & 15))) * 8);
        }
        // pin: prefetch issue stays ABOVE the MFMA cluster (no sinking)
        __builtin_amdgcn_sched_barrier(0);
        #pragma unroll
        for (int m = 0; m < 4; ++m) {
            acc[m][0] = __builtin_amdgcn_mfma_f32_16x16x32_bf16(aR[q][m], bR[q][0], acc[m][0], 0, 0, 0);
            acc[m][1] = __builtin_amdgcn_mfma_f32_16x16x32_bf16(aR[q][m], bR[q][1], acc[m][1], 0, 0, 0);
        }
        __builtin_amdgcn_sched_barrier(0);
    }

    // store: D col = lane&15 -> px, row = (lane>>4)*4 + r -> o
    int row = rp * 2 + wr;
    float* op = out + (size_t)b * COUT * NN * NN + (size_t)row * NN;
    #pragma unroll
    for (int m = 0; m < 4; ++m) {
        #pragma unroll
        for (int n = 0; n < 2; ++n) {
            int p = pb0 + wp * 32 + n * 16 + l15;
            #pragma unroll
            for (int r = 0; r < 4; ++r) {
                int o = ob + m * 16 + lg * 4 + r;
                op[(size_t)o * (NN * NN) + p] = acc[m][n][r];
            }
        }
    }
}

// ---------------------------------------------------------------------------
// fallback: naive direct conv (only if workspace too small)
// ---------------------------------------------------------------------------
__global__ __launch_bounds__(256) void conv_naive_kernel(const float* __restrict__ x,
                                                         const float* __restrict__ kern,
                                                         float* __restrict__ out) {
    size_t idx = (size_t)blockIdx.x * 256 + threadIdx.x;
    int p = idx & 127;
    size_t t = idx >> 7;
    int i = t & 127; t >>= 7;
    int o = t & 127;
    int b = (int)(t >> 7);
    float s = 0.f;
    for (int c = 0; c < CIN; ++c) {
        #pragma unroll
        for (int k = 0; k < 3; ++k) {
            int r = i + k - 1;
            if (r < 0 || r >= NN) continue;
            #pragma unroll
            for (int d = 0; d < 3; ++d) {
                int qq = p + d - 1;
                if (qq < 0 || qq >= NN) continue;
                s += kern[(((size_t)o * CIN + c) * 3 + k) * 3 + d]
                   * x[(((size_t)b * CIN + c) * NN + r) * NN + qq];
            }
        }
    }
    out[idx] = s;
}

extern "C" void kernel_launch(void* const* d_in, const int* in_sizes, int n_in,
                              void* d_out, int out_size, void* d_ws, size_t ws_size,
                              hipStream_t stream) {
    const float* x    = (const float*)d_in[0];
    const float* kern = (const float*)d_in[1];
    float* out = (float*)d_out;

    const size_t xT_bytes  = (size_t)B_ * NN * ROWE * 2;        // 136,314,880
    const size_t kT_bytes  = (size_t)9 * 16 * 128 * 8 * 2;      //     294,912

    if (ws_size >= xT_bytes + kT_bytes) {
        unsigned short* xT  = (unsigned short*)d_ws;
        unsigned short* kT2 = (unsigned short*)((char*)d_ws + xT_bytes);
        hipLaunchKernelGGL(xpose_kernel, dim3(B_ * NN), dim3(256), 0, stream, x, xT);
        hipLaunchKernelGGL(ktrans_kernel, dim3(576), dim3(256), 0, stream, kern, kT2);
        hipLaunchKernelGGL(conv_mfma17_kernel, dim3(4096), dim3(512), 0, stream, xT, kT2, out);
    } else {
        hipLaunchKernelGGL(conv_naive_kernel, dim3(67108864 / 256), dim3(256), 0, stream,
                           x, kern, out);
    }
}